// Round 1
// baseline (326.374 us; speedup 1.0000x reference)
//
#include <hip/hip_runtime.h>
#include <hip/hip_bf16.h>

#define BIGF 99999999.0f
#define NPP 4096
#define BB 4

// ---------- helpers ----------

__device__ __forceinline__ float rl(float v, int l) {
    return __int_as_float(__builtin_amdgcn_readlane(__float_as_int(v), l));
}

template <typename T>
__device__ __forceinline__ T bitonic_sort64(T v, int lane) {
    #pragma unroll
    for (int k = 2; k <= 64; k <<= 1) {
        #pragma unroll
        for (int j = k >> 1; j > 0; j >>= 1) {
            T p = __shfl_xor(v, j);
            bool up  = ((lane & k) == 0);
            bool low = ((lane & j) == 0);
            T mn = (v < p) ? v : p;
            T mx = (v < p) ? p : v;
            v = (up == low) ? mn : mx;
        }
    }
    return v;
}

// dist exactly as reference: d2 = (n2i + n2j) - 2*dot; dist = sqrt(max(d2,0));
// dist==0 -> BIG; j==i -> BIG.  fmaf(-2,dot,s) == s - 2*dot bit-exactly (2*dot exact).
__device__ __forceinline__ float dist_of(const float* qf, float n2i,
                                         const float* xj, float n2j,
                                         int j, int iq) {
    float dot = 0.f;
    #pragma unroll
    for (int f = 0; f < 8; ++f) dot = fmaf(qf[f], xj[f], dot);
    float s  = n2i + n2j;
    float d2 = fmaf(-2.0f, dot, s);
    float dist = sqrtf(fmaxf(d2, 0.0f));
    if (dist == 0.0f || j == iq) dist = BIGF;
    return dist;
}

// ---------- kernel 1: z projections ----------

__global__ void zz_kernel(const float* __restrict__ z,
                          const float* __restrict__ Wmz, const float* __restrict__ bmz,
                          const float* __restrict__ Wvz, const float* __restrict__ bvz,
                          float* __restrict__ zzm, float* __restrict__ zzv) {
    int b = blockIdx.x, l = threadIdx.x;
    float sv = 0.f;
    for (int p = 0; p < 64; ++p) sv = fmaf(z[b * 64 + p], Wvz[p * 64 + l], sv);
    zzv[b * 64 + l] = sv + bvz[l];
    if (l < 8) {
        float sm = 0.f;
        for (int p = 0; p < 64; ++p) sm = fmaf(z[b * 64 + p], Wmz[p * 8 + l], sm);
        zzm[b * 8 + l] = sm + bmz[l];
    }
}

// ---------- kernel 2: exact knn top-16 ----------
// One wave handles NQ=8 queries. Pass1: per-lane min of dist-bits.
// Threshold T = 16th smallest of 64 lane-minima (>=16 candidates <= T guaranteed).
// Pass2: recompute, compact (distbits<<32)|j for distbits<=T into LDS.
// Pass3: bitonic sort u64 across 64 lanes, lanes 0..15 write sorted idx.

#define NQ 8

__global__ __launch_bounds__(256) void knn_kernel(const float* __restrict__ x,
                                                  int* __restrict__ idx_out) {
    int lane = threadIdx.x & 63;
    int wid  = threadIdx.x >> 6;
    int gw   = blockIdx.x * 4 + wid;      // 0..2047
    int b    = gw >> 9;                   // 512 waves per batch
    int q0   = (gw & 511) * NQ;
    const float* xb = x + b * NPP * 8;

    // load queries (broadcast loads)
    float qf[NQ][8];
    float n2i[NQ];
    #pragma unroll
    for (int q = 0; q < NQ; ++q) {
        const float* p = xb + (q0 + q) * 8;
        #pragma unroll
        for (int f = 0; f < 8; ++f) qf[q][f] = p[f];
        float s = 0.f;
        #pragma unroll
        for (int f = 0; f < 8; ++f) s = fmaf(qf[q][f], qf[q][f], s);
        n2i[q] = s;
    }

    // pass 1: per-lane minimum of dist bits
    unsigned minb[NQ];
    #pragma unroll
    for (int q = 0; q < NQ; ++q) minb[q] = 0xFFFFFFFFu;

    for (int t = 0; t < 64; ++t) {
        int j = t * 64 + lane;
        const float4* pj = (const float4*)(xb + j * 8);
        float4 a = pj[0], c = pj[1];
        float xj[8] = {a.x, a.y, a.z, a.w, c.x, c.y, c.z, c.w};
        float n2j = 0.f;
        #pragma unroll
        for (int f = 0; f < 8; ++f) n2j = fmaf(xj[f], xj[f], n2j);
        #pragma unroll
        for (int q = 0; q < NQ; ++q) {
            float dist = dist_of(qf[q], n2i[q], xj, n2j, j, q0 + q);
            unsigned kb = __float_as_uint(dist);
            minb[q] = (kb < minb[q]) ? kb : minb[q];
        }
    }

    // threshold: 16th smallest of the 64 lane minima
    unsigned T[NQ];
    #pragma unroll
    for (int q = 0; q < NQ; ++q) {
        unsigned v = bitonic_sort64(minb[q], lane);
        T[q] = (unsigned)__shfl((int)v, 15);
    }

    // pass 2: compact candidates <= T into LDS
    __shared__ unsigned long long buf[4][NQ][64];
    int cnt[NQ];
    #pragma unroll
    for (int q = 0; q < NQ; ++q) cnt[q] = 0;

    for (int t = 0; t < 64; ++t) {
        int j = t * 64 + lane;
        const float4* pj = (const float4*)(xb + j * 8);
        float4 a = pj[0], c = pj[1];
        float xj[8] = {a.x, a.y, a.z, a.w, c.x, c.y, c.z, c.w};
        float n2j = 0.f;
        #pragma unroll
        for (int f = 0; f < 8; ++f) n2j = fmaf(xj[f], xj[f], n2j);
        #pragma unroll
        for (int q = 0; q < NQ; ++q) {
            float dist = dist_of(qf[q], n2i[q], xj, n2j, j, q0 + q);
            unsigned kb = __float_as_uint(dist);
            bool pred = (kb <= T[q]);
            unsigned long long m = __ballot(pred);
            if (m) {
                int ofs = cnt[q] + __popcll(m & ((1ull << lane) - 1ull));
                if (pred && ofs < 64) {
                    buf[wid][q][ofs] = ((unsigned long long)kb << 32) | (unsigned)j;
                }
                cnt[q] += __popcll(m);
            }
        }
    }
    __syncthreads();

    // pass 3: sort and emit
    #pragma unroll 1
    for (int q = 0; q < NQ; ++q) {
        int c = cnt[q] < 64 ? cnt[q] : 64;
        unsigned long long key = (lane < c) ? buf[wid][q][lane] : ~0ull;
        key = bitonic_sort64(key, lane);
        if (lane < 16) {
            idx_out[((long)(b * NPP + q0 + q)) * 16 + lane] = (int)(key & 0xFFFFFFFFull);
        }
    }
}

// ---------- kernel 3: features + output heads ----------
// One wave per point (4 waves/block). Stage1: lane=(rg,k) computes the 4 moment
// sets for rows r=p*4+rg. m-moments -> padded LDS; v-moments stay in registers
// and are broadcast via v_readlane in stage 3.

__global__ __launch_bounds__(256) void feat_kernel(
    const float* __restrict__ x, const int* __restrict__ idxw,
    const float* __restrict__ Wm2, const float* __restrict__ bm2,
    const float* __restrict__ Wm3, const float* __restrict__ bm3,
    const float* __restrict__ Wv2, const float* __restrict__ bv2,
    const float* __restrict__ Wv3, const float* __restrict__ bv3,
    const float* __restrict__ Wmx, const float* __restrict__ bmx,
    const float* __restrict__ Wvx, const float* __restrict__ bvx,
    const float* __restrict__ zzm, const float* __restrict__ zzv,
    float* __restrict__ xout, float* __restrict__ zout)
{
    int lane = threadIdx.x & 63;
    int wid  = threadIdx.x >> 6;
    int pn   = blockIdx.x * 4 + wid;          // global point id
    int b    = pn >> 12;
    const float* xb = x + b * NPP * 8;

    __shared__ float xg_s[4][16][8];
    __shared__ float mm_s[4][15][36];         // stride 36: 16B-aligned rows, conflict-free
    __shared__ float wmx_s[32][8];
    __shared__ float bzm_s[8];
    __shared__ float zpart[4][64];

    // block-shared preloads
    if (threadIdx.x < 256) {
        wmx_s[threadIdx.x >> 3][threadIdx.x & 7] = Wmx[threadIdx.x];
    }
    if (threadIdx.x < 8) bzm_s[threadIdx.x] = bmx[threadIdx.x] + zzm[b * 8 + threadIdx.x];

    // per-lane weights (k = lane & 15)
    int k = lane & 15;
    float w20 = Wm2[k], w21 = Wm2[16 + k], bb2 = bm2[k];
    float w30 = Wm3[k], w31 = Wm3[16 + k], w32 = Wm3[32 + k], bb3 = bm3[k];
    float u20 = Wv2[k], u21 = Wv2[16 + k], cc2 = bv2[k];
    float u30 = Wv3[k], u31 = Wv3[16 + k], u32 = Wv3[32 + k], cc3 = bv3[k];
    float wvx[32];
    #pragma unroll
    for (int c = 0; c < 32; ++c) wvx[c] = Wvx[c * 64 + lane];
    float bz3 = bvx[lane] + zzv[b * 64 + lane];

    // gather 16 neighbors
    if (lane < 16) {
        int myid = idxw[(long)pn * 16 + lane];
        const float4* ps = (const float4*)(xb + (long)myid * 8);
        float4 a = ps[0], c4 = ps[1];
        *((float4*)&xg_s[wid][lane][0]) = a;
        *((float4*)&xg_s[wid][lane][4]) = c4;
    }
    __syncthreads();

    float g0[8];
    #pragma unroll
    for (int f = 0; f < 8; ++f) g0[f] = xg_s[wid][0][f];

    // stage 1: moments (mean over d folded as exact *0.125)
    float am2[4], am3[4], av2[4], av3[4];
    #pragma unroll
    for (int p = 0; p < 4; ++p) {
        int rg = lane >> 4;
        int r  = p * 4 + rg;
        int rc = (r < 14) ? r : 14;
        int i2  = rc + 1;
        int i3a = (rc < 14) ? 1 : 2;
        int i3b = (rc < 14) ? rc + 2 : 3;
        const float* G1  = xg_s[wid][i2];
        const float* G3a = xg_s[wid][i3a];
        const float* G3b = xg_s[wid][i3b];
        float s2 = 0.f, s3 = 0.f, t2 = 0.f, t3 = 0.f;
        #pragma unroll
        for (int d = 0; d < 8; ++d) {
            float gz = g0[d], g1 = G1[d], ga = G3a[d], gb = G3b[d];
            float y2 = fmaf(gz, w20, fmaf(g1, w21, bb2));
            s2 += fmaxf(y2, 0.f);
            float y3 = fmaf(gz, w30, fmaf(ga, w31, fmaf(gb, w32, bb3)));
            s3 += fmaxf(y3, 0.f);
            float z2 = fmaf(gz, u20, fmaf(g1, u21, cc2));
            t2 += fmaxf(z2, 0.f);
            float z3 = fmaf(gz, u30, fmaf(ga, u31, fmaf(gb, u32, cc3)));
            t3 += fmaxf(z3, 0.f);
        }
        am2[p] = s2 * 0.125f; am3[p] = s3 * 0.125f;
        av2[p] = t2 * 0.125f; av3[p] = t3 * 0.125f;
        if (r < 15) {
            mm_s[wid][r][k]      = am2[p];
            mm_s[wid][r][16 + k] = am3[p];
        }
    }
    __syncthreads();

    // stage 2: x head. lane=(r-group, do). two halves cover r=0..15 (r=15 masked).
    float xa = 0.f;
    #pragma unroll
    for (int half = 0; half < 2; ++half) {
        int r   = (lane >> 3) + half * 8;
        int doo = lane & 7;
        float s = 0.f;
        if (r < 15) {
            s = bzm_s[doo];
            #pragma unroll
            for (int c = 0; c < 32; ++c)
                s = fmaf(mm_s[wid][r][c], wmx_s[c][doo], s);
            s = fmaxf(s, 0.f);
        }
        xa += s;
    }
    xa += __shfl_xor(xa, 8);
    xa += __shfl_xor(xa, 16);
    xa += __shfl_xor(xa, 32);
    float xv = xa * (1.0f / 15.0f);
    if (lane < 8) xout[(long)pn * 8 + lane] = xv;

    // stage 3: z head. lane = nm. v-moments broadcast from registers via readlane.
    float za = 0.f;
    #pragma unroll
    for (int r = 0; r < 15; ++r) {
        float s = bz3;
        const int p  = r >> 2;
        const int sb = (r & 3) * 16;
        #pragma unroll
        for (int c = 0; c < 16; ++c)
            s = fmaf(rl(av2[p], sb + c), wvx[c], s);
        #pragma unroll
        for (int c = 0; c < 16; ++c)
            s = fmaf(rl(av3[p], sb + c), wvx[16 + c], s);
        za += fmaxf(s, 0.f);
    }
    za *= (1.0f / 61440.0f);

    zpart[wid][lane] = za;
    __syncthreads();
    if (wid == 0) {
        float ssum = zpart[0][lane] + zpart[1][lane] + zpart[2][lane] + zpart[3][lane];
        atomicAdd(&zout[b * 64 + lane], ssum);
    }
}

// ---------- launcher ----------

extern "C" void kernel_launch(void* const* d_in, const int* in_sizes, int n_in,
                              void* d_out, int out_size, void* d_ws, size_t ws_size,
                              hipStream_t stream) {
    const float* x   = (const float*)d_in[0];
    const float* z   = (const float*)d_in[1];
    const float* Wm2 = (const float*)d_in[2];
    const float* bm2 = (const float*)d_in[3];
    const float* Wm3 = (const float*)d_in[4];
    const float* bm3 = (const float*)d_in[5];
    const float* Wv2 = (const float*)d_in[6];
    const float* bv2 = (const float*)d_in[7];
    const float* Wv3 = (const float*)d_in[8];
    const float* bv3 = (const float*)d_in[9];
    const float* Wmx = (const float*)d_in[10];
    const float* bmx = (const float*)d_in[11];
    const float* Wvx = (const float*)d_in[12];
    const float* bvx = (const float*)d_in[13];
    const float* Wmz = (const float*)d_in[14];
    const float* bmz = (const float*)d_in[15];
    const float* Wvz = (const float*)d_in[16];
    const float* bvz = (const float*)d_in[17];

    float* out  = (float*)d_out;
    int*   idxw = (int*)d_ws;
    float* zzm  = (float*)((char*)d_ws + (size_t)BB * NPP * 16 * 4);
    float* zzv  = zzm + BB * 8;
    float* xout = out;                 // B*NP*8 = 131072 floats
    float* zout = out + BB * NPP * 8;  // B*64 = 256 floats

    hipMemsetAsync(zout, 0, BB * 64 * sizeof(float), stream);
    zz_kernel<<<dim3(BB), dim3(64), 0, stream>>>(z, Wmz, bmz, Wvz, bvz, zzm, zzv);
    knn_kernel<<<dim3(512), dim3(256), 0, stream>>>(x, idxw);
    feat_kernel<<<dim3(4096), dim3(256), 0, stream>>>(
        x, idxw, Wm2, bm2, Wm3, bm3, Wv2, bv2, Wv3, bv3,
        Wmx, bmx, Wvx, bvx, zzm, zzv, xout, zout);
}

// Round 2
// 281.083 us; speedup vs baseline: 1.1611x; 1.1611x over previous
//
#include <hip/hip_runtime.h>
#include <hip/hip_bf16.h>

#define BIGF 99999999.0f
#define NPP 4096
#define BB 4

// ---------- helpers ----------

__device__ __forceinline__ float rl(float v, int l) {
    return __int_as_float(__builtin_amdgcn_readlane(__float_as_int(v), l));
}

template <typename T>
__device__ __forceinline__ T bitonic_sort64(T v, int lane) {
    #pragma unroll
    for (int k = 2; k <= 64; k <<= 1) {
        #pragma unroll
        for (int j = k >> 1; j > 0; j >>= 1) {
            T p = __shfl_xor(v, j);
            bool up  = ((lane & k) == 0);
            bool low = ((lane & j) == 0);
            T mn = (v < p) ? v : p;
            T mx = (v < p) ? p : v;
            v = (up == low) ? mn : mx;
        }
    }
    return v;
}

// ---------- kernel 0: per-point squared norms ----------

__global__ __launch_bounds__(256) void n2_kernel(const float* __restrict__ x,
                                                 float* __restrict__ n2tab) {
    int i = blockIdx.x * 256 + threadIdx.x;       // 0..16383
    const float4* p = (const float4*)(x + (long)i * 8);
    float4 a = p[0], c = p[1];
    float s = 0.f;
    s = fmaf(a.x, a.x, s); s = fmaf(a.y, a.y, s);
    s = fmaf(a.z, a.z, s); s = fmaf(a.w, a.w, s);
    s = fmaf(c.x, c.x, s); s = fmaf(c.y, c.y, s);
    s = fmaf(c.z, c.z, s); s = fmaf(c.w, c.w, s);
    n2tab[i] = s;
}

// ---------- kernel 1: z projections ----------

__global__ void zz_kernel(const float* __restrict__ z,
                          const float* __restrict__ Wmz, const float* __restrict__ bmz,
                          const float* __restrict__ Wvz, const float* __restrict__ bvz,
                          float* __restrict__ zzm, float* __restrict__ zzv) {
    int b = blockIdx.x, l = threadIdx.x;
    float sv = 0.f;
    for (int p = 0; p < 64; ++p) sv = fmaf(z[b * 64 + p], Wvz[p * 64 + l], sv);
    zzv[b * 64 + l] = sv + bvz[l];
    if (l < 8) {
        float sm = 0.f;
        for (int p = 0; p < 64; ++p) sm = fmaf(z[b * 64 + p], Wmz[p * 8 + l], sm);
        zzm[b * 8 + l] = sm + bmz[l];
    }
}

// ---------- kernel 2: exact knn top-16, one wave per query ----------
// Selection key = d2 bits (sqrt is monotone; d2<=0 or j==q -> BIG).
// Pass 1: compute all 4096 d2 keys, store in LDS, track per-lane min.
// Threshold T = 16th smallest of the 64 lane minima (>=16 candidates <= T).
// Pass 2: scan LDS keys, compact (key<<32)|j candidates, u64 bitonic sort,
// lanes 0..15 emit sorted neighbor indices (ties broken by lower index,
// matching jax.lax.top_k).

__global__ __launch_bounds__(64) void knn_kernel(const float* __restrict__ x,
                                                 const float* __restrict__ n2tab,
                                                 int* __restrict__ idx_out) {
    __shared__ unsigned sd[4096];
    __shared__ unsigned long long cand[64];

    int lane = threadIdx.x;
    int qg   = blockIdx.x;            // 0..16383
    int b    = qg >> 12;
    int q    = qg & 4095;
    const float* xb = x + (long)b * NPP * 8;
    const float* nb = n2tab + b * NPP;

    // query (wave-uniform -> scalar loads)
    float qf[8];
    #pragma unroll
    for (int f = 0; f < 8; ++f) qf[f] = xb[q * 8 + f];
    float n2i = nb[q];

    const unsigned BIGB = __float_as_uint(BIGF);
    unsigned minb = 0xFFFFFFFFu;

    #pragma unroll 4
    for (int t = 0; t < 64; ++t) {
        int j = t * 64 + lane;
        const float4* pj = (const float4*)(xb + j * 8);
        float4 a = pj[0], c = pj[1];
        float n2j = nb[j];
        float dot = 0.f;
        dot = fmaf(qf[0], a.x, dot); dot = fmaf(qf[1], a.y, dot);
        dot = fmaf(qf[2], a.z, dot); dot = fmaf(qf[3], a.w, dot);
        dot = fmaf(qf[4], c.x, dot); dot = fmaf(qf[5], c.y, dot);
        dot = fmaf(qf[6], c.z, dot); dot = fmaf(qf[7], c.w, dot);
        float d2 = fmaf(-2.0f, dot, n2i + n2j);
        unsigned kb = (d2 <= 0.0f || j == q) ? BIGB : __float_as_uint(d2);
        sd[j] = kb;
        minb = (kb < minb) ? kb : minb;
    }

    // threshold: 16th smallest of the 64 lane minima
    unsigned v = bitonic_sort64(minb, lane);
    unsigned T = (unsigned)__shfl((int)v, 15);

    // pass 2: compact candidates <= T
    int cnt = 0;
    for (int t = 0; t < 64; ++t) {
        unsigned kb = sd[t * 64 + lane];
        bool pred = (kb <= T);
        unsigned long long m = __ballot(pred);
        if (m) {
            int ofs = cnt + __popcll(m & ((1ull << lane) - 1ull));
            if (pred && ofs < 64) {
                cand[ofs] = ((unsigned long long)kb << 32) | (unsigned)(t * 64 + lane);
            }
            cnt += __popcll(m);
        }
    }
    __syncthreads();

    int c = cnt < 64 ? cnt : 64;
    unsigned long long key = (lane < c) ? cand[lane] : ~0ull;
    key = bitonic_sort64(key, lane);
    if (lane < 16) {
        idx_out[(long)qg * 16 + lane] = (int)(key & 0xFFFFFFFFull);
    }
}

// ---------- kernel 3: features + output heads ----------

__global__ __launch_bounds__(256) void feat_kernel(
    const float* __restrict__ x, const int* __restrict__ idxw,
    const float* __restrict__ Wm2, const float* __restrict__ bm2,
    const float* __restrict__ Wm3, const float* __restrict__ bm3,
    const float* __restrict__ Wv2, const float* __restrict__ bv2,
    const float* __restrict__ Wv3, const float* __restrict__ bv3,
    const float* __restrict__ Wmx, const float* __restrict__ bmx,
    const float* __restrict__ Wvx, const float* __restrict__ bvx,
    const float* __restrict__ zzm, const float* __restrict__ zzv,
    float* __restrict__ xout, float* __restrict__ zout)
{
    int lane = threadIdx.x & 63;
    int wid  = threadIdx.x >> 6;
    int pn   = blockIdx.x * 4 + wid;          // global point id
    int b    = pn >> 12;
    const float* xb = x + b * NPP * 8;

    __shared__ float xg_s[4][16][8];
    __shared__ float mm_s[4][15][36];         // stride 36: conflict-free
    __shared__ float wmx_s[32][8];
    __shared__ float bzm_s[8];
    __shared__ float zpart[4][64];

    if (threadIdx.x < 256) {
        wmx_s[threadIdx.x >> 3][threadIdx.x & 7] = Wmx[threadIdx.x];
    }
    if (threadIdx.x < 8) bzm_s[threadIdx.x] = bmx[threadIdx.x] + zzm[b * 8 + threadIdx.x];

    int k = lane & 15;
    float w20 = Wm2[k], w21 = Wm2[16 + k], bb2 = bm2[k];
    float w30 = Wm3[k], w31 = Wm3[16 + k], w32 = Wm3[32 + k], bb3 = bm3[k];
    float u20 = Wv2[k], u21 = Wv2[16 + k], cc2 = bv2[k];
    float u30 = Wv3[k], u31 = Wv3[16 + k], u32 = Wv3[32 + k], cc3 = bv3[k];
    float wvx[32];
    #pragma unroll
    for (int c = 0; c < 32; ++c) wvx[c] = Wvx[c * 64 + lane];
    float bz3 = bvx[lane] + zzv[b * 64 + lane];

    if (lane < 16) {
        int myid = idxw[(long)pn * 16 + lane];
        const float4* ps = (const float4*)(xb + (long)myid * 8);
        float4 a = ps[0], c4 = ps[1];
        *((float4*)&xg_s[wid][lane][0]) = a;
        *((float4*)&xg_s[wid][lane][4]) = c4;
    }
    __syncthreads();

    float g0[8];
    #pragma unroll
    for (int f = 0; f < 8; ++f) g0[f] = xg_s[wid][0][f];

    float am2[4], am3[4], av2[4], av3[4];
    #pragma unroll
    for (int p = 0; p < 4; ++p) {
        int rg = lane >> 4;
        int r  = p * 4 + rg;
        int rc = (r < 14) ? r : 14;
        int i2  = rc + 1;
        int i3a = (rc < 14) ? 1 : 2;
        int i3b = (rc < 14) ? rc + 2 : 3;
        const float* G1  = xg_s[wid][i2];
        const float* G3a = xg_s[wid][i3a];
        const float* G3b = xg_s[wid][i3b];
        float s2 = 0.f, s3 = 0.f, t2 = 0.f, t3 = 0.f;
        #pragma unroll
        for (int d = 0; d < 8; ++d) {
            float gz = g0[d], g1 = G1[d], ga = G3a[d], gb = G3b[d];
            float y2 = fmaf(gz, w20, fmaf(g1, w21, bb2));
            s2 += fmaxf(y2, 0.f);
            float y3 = fmaf(gz, w30, fmaf(ga, w31, fmaf(gb, w32, bb3)));
            s3 += fmaxf(y3, 0.f);
            float z2 = fmaf(gz, u20, fmaf(g1, u21, cc2));
            t2 += fmaxf(z2, 0.f);
            float z3 = fmaf(gz, u30, fmaf(ga, u31, fmaf(gb, u32, cc3)));
            t3 += fmaxf(z3, 0.f);
        }
        am2[p] = s2 * 0.125f; am3[p] = s3 * 0.125f;
        av2[p] = t2 * 0.125f; av3[p] = t3 * 0.125f;
        if (r < 15) {
            mm_s[wid][r][k]      = am2[p];
            mm_s[wid][r][16 + k] = am3[p];
        }
    }
    __syncthreads();

    float xa = 0.f;
    #pragma unroll
    for (int half = 0; half < 2; ++half) {
        int r   = (lane >> 3) + half * 8;
        int doo = lane & 7;
        float s = 0.f;
        if (r < 15) {
            s = bzm_s[doo];
            #pragma unroll
            for (int c = 0; c < 32; ++c)
                s = fmaf(mm_s[wid][r][c], wmx_s[c][doo], s);
            s = fmaxf(s, 0.f);
        }
        xa += s;
    }
    xa += __shfl_xor(xa, 8);
    xa += __shfl_xor(xa, 16);
    xa += __shfl_xor(xa, 32);
    float xv = xa * (1.0f / 15.0f);
    if (lane < 8) xout[(long)pn * 8 + lane] = xv;

    float za = 0.f;
    #pragma unroll
    for (int r = 0; r < 15; ++r) {
        float s = bz3;
        const int p  = r >> 2;
        const int sb = (r & 3) * 16;
        #pragma unroll
        for (int c = 0; c < 16; ++c)
            s = fmaf(rl(av2[p], sb + c), wvx[c], s);
        #pragma unroll
        for (int c = 0; c < 16; ++c)
            s = fmaf(rl(av3[p], sb + c), wvx[16 + c], s);
        za += fmaxf(s, 0.f);
    }
    za *= (1.0f / 61440.0f);

    zpart[wid][lane] = za;
    __syncthreads();
    if (wid == 0) {
        float ssum = zpart[0][lane] + zpart[1][lane] + zpart[2][lane] + zpart[3][lane];
        atomicAdd(&zout[b * 64 + lane], ssum);
    }
}

// ---------- launcher ----------

extern "C" void kernel_launch(void* const* d_in, const int* in_sizes, int n_in,
                              void* d_out, int out_size, void* d_ws, size_t ws_size,
                              hipStream_t stream) {
    const float* x   = (const float*)d_in[0];
    const float* z   = (const float*)d_in[1];
    const float* Wm2 = (const float*)d_in[2];
    const float* bm2 = (const float*)d_in[3];
    const float* Wm3 = (const float*)d_in[4];
    const float* bm3 = (const float*)d_in[5];
    const float* Wv2 = (const float*)d_in[6];
    const float* bv2 = (const float*)d_in[7];
    const float* Wv3 = (const float*)d_in[8];
    const float* bv3 = (const float*)d_in[9];
    const float* Wmx = (const float*)d_in[10];
    const float* bmx = (const float*)d_in[11];
    const float* Wvx = (const float*)d_in[12];
    const float* bvx = (const float*)d_in[13];
    const float* Wmz = (const float*)d_in[14];
    const float* bmz = (const float*)d_in[15];
    const float* Wvz = (const float*)d_in[16];
    const float* bvz = (const float*)d_in[17];

    float* out  = (float*)d_out;
    int*   idxw = (int*)d_ws;                                   // 1 MB
    float* zzm  = (float*)((char*)d_ws + (size_t)BB * NPP * 16 * 4);
    float* zzv  = zzm + BB * 8;
    float* n2t  = zzv + BB * 64;                                // 64 KB
    float* xout = out;                 // B*NP*8 = 131072 floats
    float* zout = out + BB * NPP * 8;  // B*64 = 256 floats

    hipMemsetAsync(zout, 0, BB * 64 * sizeof(float), stream);
    n2_kernel<<<dim3(BB * NPP / 256), dim3(256), 0, stream>>>(x, n2t);
    zz_kernel<<<dim3(BB), dim3(64), 0, stream>>>(z, Wmz, bmz, Wvz, bvz, zzm, zzv);
    knn_kernel<<<dim3(BB * NPP), dim3(64), 0, stream>>>(x, n2t, idxw);
    feat_kernel<<<dim3(4096), dim3(256), 0, stream>>>(
        x, idxw, Wm2, bm2, Wm3, bm3, Wv2, bv2, Wv3, bv3,
        Wmx, bmx, Wvx, bvx, zzm, zzv, xout, zout);
}

// Round 3
// 266.735 us; speedup vs baseline: 1.2236x; 1.0538x over previous
//
#include <hip/hip_runtime.h>
#include <hip/hip_bf16.h>

#define BIGF 99999999.0f
#define NPP 4096
#define BB 4
#define NQ 4

// ---------- helpers ----------

__device__ __forceinline__ float rl(float v, int l) {
    return __int_as_float(__builtin_amdgcn_readlane(__float_as_int(v), l));
}

template <typename T>
__device__ __forceinline__ T bitonic_sort64(T v, int lane) {
    #pragma unroll
    for (int k = 2; k <= 64; k <<= 1) {
        #pragma unroll
        for (int j = k >> 1; j > 0; j >>= 1) {
            T p = __shfl_xor(v, j);
            bool up  = ((lane & k) == 0);
            bool low = ((lane & j) == 0);
            T mn = (v < p) ? v : p;
            T mx = (v < p) ? p : v;
            v = (up == low) ? mn : mx;
        }
    }
    return v;
}

// selection key: d2 bits (sqrt is monotone, identical selection); d2<=0 or j==q -> BIG
__device__ __forceinline__ unsigned d2key(const float* qf, float n2i,
                                          const float4& a, const float4& c,
                                          float n2j, int j, int q) {
    float dot = 0.f;
    dot = fmaf(qf[0], a.x, dot); dot = fmaf(qf[1], a.y, dot);
    dot = fmaf(qf[2], a.z, dot); dot = fmaf(qf[3], a.w, dot);
    dot = fmaf(qf[4], c.x, dot); dot = fmaf(qf[5], c.y, dot);
    dot = fmaf(qf[6], c.z, dot); dot = fmaf(qf[7], c.w, dot);
    float d2 = fmaf(-2.0f, dot, n2i + n2j);
    return (d2 <= 0.0f || j == q) ? __float_as_uint(BIGF) : __float_as_uint(d2);
}

// ---------- kernel 0: per-point squared norms (+ zero zout) ----------

__global__ __launch_bounds__(256) void n2_kernel(const float* __restrict__ x,
                                                 float* __restrict__ n2tab,
                                                 float* __restrict__ zout) {
    int i = blockIdx.x * 256 + threadIdx.x;       // 0..16383
    if (blockIdx.x == 0) zout[threadIdx.x] = 0.f; // 256 floats
    const float4* p = (const float4*)(x + (long)i * 8);
    float4 a = p[0], c = p[1];
    float s = 0.f;
    s = fmaf(a.x, a.x, s); s = fmaf(a.y, a.y, s);
    s = fmaf(a.z, a.z, s); s = fmaf(a.w, a.w, s);
    s = fmaf(c.x, c.x, s); s = fmaf(c.y, c.y, s);
    s = fmaf(c.z, c.z, s); s = fmaf(c.w, c.w, s);
    n2tab[i] = s;
}

// ---------- kernel 1: z projections ----------

__global__ void zz_kernel(const float* __restrict__ z,
                          const float* __restrict__ Wmz, const float* __restrict__ bmz,
                          const float* __restrict__ Wvz, const float* __restrict__ bvz,
                          float* __restrict__ zzm, float* __restrict__ zzv) {
    int b = blockIdx.x, l = threadIdx.x;
    float sv = 0.f;
    for (int p = 0; p < 64; ++p) sv = fmaf(z[b * 64 + p], Wvz[p * 64 + l], sv);
    zzv[b * 64 + l] = sv + bvz[l];
    if (l < 8) {
        float sm = 0.f;
        for (int p = 0; p < 64; ++p) sm = fmaf(z[b * 64 + p], Wmz[p * 8 + l], sm);
        zzm[b * 8 + l] = sm + bmz[l];
    }
}

// ---------- kernel 2: exact knn top-16, NQ=4 queries per wave ----------
// Pass 1: per-lane min of d2-key over all 4096 candidates (per query).
// T = 16th smallest of the 64 lane minima (>=16 candidates <= T guaranteed).
// Pass 2: recompute keys (bit-identical expression), ballot-compact
// (key<<32)|j for key<=T, u64 bitonic sort, lanes 0..15 emit indices.
// Waves are independent: no __syncthreads needed.

__global__ __launch_bounds__(256) void knn_kernel(const float* __restrict__ x,
                                                  const float* __restrict__ n2tab,
                                                  int* __restrict__ idx_out) {
    __shared__ unsigned long long cand[4][NQ][64];

    int lane = threadIdx.x & 63;
    int wid  = threadIdx.x >> 6;
    int gw   = blockIdx.x * 4 + wid;      // 0..4095
    int q0   = gw * NQ;                   // global query base (0..16383)
    int b    = q0 >> 12;
    int qloc = q0 & 4095;
    const float* xb = x + (long)b * NPP * 8;
    const float* nb = n2tab + b * NPP;

    // queries (wave-uniform -> scalar loads)
    float qf[NQ][8];
    float n2i[NQ];
    #pragma unroll
    for (int q = 0; q < NQ; ++q) {
        #pragma unroll
        for (int f = 0; f < 8; ++f) qf[q][f] = xb[(qloc + q) * 8 + f];
        n2i[q] = nb[qloc + q];
    }

    // pass 1: per-lane min of keys
    unsigned minb[NQ];
    #pragma unroll
    for (int q = 0; q < NQ; ++q) minb[q] = 0xFFFFFFFFu;

    #pragma unroll 4
    for (int t = 0; t < 64; ++t) {
        int j = t * 64 + lane;
        const float4* pj = (const float4*)(xb + j * 8);
        float4 a = pj[0], c = pj[1];
        float n2j = nb[j];
        #pragma unroll
        for (int q = 0; q < NQ; ++q) {
            unsigned kb = d2key(qf[q], n2i[q], a, c, n2j, j, qloc + q);
            minb[q] = (kb < minb[q]) ? kb : minb[q];
        }
    }

    // thresholds: 16th smallest of the 64 lane minima
    unsigned T[NQ];
    #pragma unroll
    for (int q = 0; q < NQ; ++q) {
        unsigned v = bitonic_sort64(minb[q], lane);
        T[q] = (unsigned)__shfl((int)v, 15);
    }

    // pass 2: recompute + compact candidates <= T
    int cnt[NQ];
    #pragma unroll
    for (int q = 0; q < NQ; ++q) cnt[q] = 0;

    for (int t = 0; t < 64; ++t) {
        int j = t * 64 + lane;
        const float4* pj = (const float4*)(xb + j * 8);
        float4 a = pj[0], c = pj[1];
        float n2j = nb[j];
        #pragma unroll
        for (int q = 0; q < NQ; ++q) {
            unsigned kb = d2key(qf[q], n2i[q], a, c, n2j, j, qloc + q);
            bool pred = (kb <= T[q]);
            unsigned long long m = __ballot(pred);
            if (m) {
                int ofs = cnt[q] + __popcll(m & ((1ull << lane) - 1ull));
                if (pred && ofs < 64) {
                    cand[wid][q][ofs] = ((unsigned long long)kb << 32) | (unsigned)j;
                }
                cnt[q] += __popcll(m);
            }
        }
    }

    // sort and emit (same-wave LDS RAW: compiler inserts lgkmcnt waits)
    #pragma unroll 1
    for (int q = 0; q < NQ; ++q) {
        int c = cnt[q] < 64 ? cnt[q] : 64;
        unsigned long long key = (lane < c) ? cand[wid][q][lane] : ~0ull;
        key = bitonic_sort64(key, lane);
        if (lane < 16) {
            idx_out[(long)(q0 + q) * 16 + lane] = (int)(key & 0xFFFFFFFFull);
        }
    }
}

// ---------- kernel 3: features + output heads ----------

__global__ __launch_bounds__(256) void feat_kernel(
    const float* __restrict__ x, const int* __restrict__ idxw,
    const float* __restrict__ Wm2, const float* __restrict__ bm2,
    const float* __restrict__ Wm3, const float* __restrict__ bm3,
    const float* __restrict__ Wv2, const float* __restrict__ bv2,
    const float* __restrict__ Wv3, const float* __restrict__ bv3,
    const float* __restrict__ Wmx, const float* __restrict__ bmx,
    const float* __restrict__ Wvx, const float* __restrict__ bvx,
    const float* __restrict__ zzm, const float* __restrict__ zzv,
    float* __restrict__ xout, float* __restrict__ zout)
{
    int lane = threadIdx.x & 63;
    int wid  = threadIdx.x >> 6;
    int pn   = blockIdx.x * 4 + wid;          // global point id
    int b    = pn >> 12;
    const float* xb = x + b * NPP * 8;

    __shared__ float xg_s[4][16][8];
    __shared__ float mm_s[4][15][36];         // stride 36: conflict-free
    __shared__ float wmx_s[32][8];
    __shared__ float bzm_s[8];
    __shared__ float zpart[4][64];

    if (threadIdx.x < 256) {
        wmx_s[threadIdx.x >> 3][threadIdx.x & 7] = Wmx[threadIdx.x];
    }
    if (threadIdx.x < 8) bzm_s[threadIdx.x] = bmx[threadIdx.x] + zzm[b * 8 + threadIdx.x];

    int k = lane & 15;
    float w20 = Wm2[k], w21 = Wm2[16 + k], bb2 = bm2[k];
    float w30 = Wm3[k], w31 = Wm3[16 + k], w32 = Wm3[32 + k], bb3 = bm3[k];
    float u20 = Wv2[k], u21 = Wv2[16 + k], cc2 = bv2[k];
    float u30 = Wv3[k], u31 = Wv3[16 + k], u32 = Wv3[32 + k], cc3 = bv3[k];
    float wvx[32];
    #pragma unroll
    for (int c = 0; c < 32; ++c) wvx[c] = Wvx[c * 64 + lane];
    float bz3 = bvx[lane] + zzv[b * 64 + lane];

    if (lane < 16) {
        int myid = idxw[(long)pn * 16 + lane];
        const float4* ps = (const float4*)(xb + (long)myid * 8);
        float4 a = ps[0], c4 = ps[1];
        *((float4*)&xg_s[wid][lane][0]) = a;
        *((float4*)&xg_s[wid][lane][4]) = c4;
    }
    __syncthreads();

    float g0[8];
    #pragma unroll
    for (int f = 0; f < 8; ++f) g0[f] = xg_s[wid][0][f];

    float am2[4], am3[4], av2[4], av3[4];
    #pragma unroll
    for (int p = 0; p < 4; ++p) {
        int rg = lane >> 4;
        int r  = p * 4 + rg;
        int rc = (r < 14) ? r : 14;
        int i2  = rc + 1;
        int i3a = (rc < 14) ? 1 : 2;
        int i3b = (rc < 14) ? rc + 2 : 3;
        const float* G1  = xg_s[wid][i2];
        const float* G3a = xg_s[wid][i3a];
        const float* G3b = xg_s[wid][i3b];
        float s2 = 0.f, s3 = 0.f, t2 = 0.f, t3 = 0.f;
        #pragma unroll
        for (int d = 0; d < 8; ++d) {
            float gz = g0[d], g1 = G1[d], ga = G3a[d], gb = G3b[d];
            float y2 = fmaf(gz, w20, fmaf(g1, w21, bb2));
            s2 += fmaxf(y2, 0.f);
            float y3 = fmaf(gz, w30, fmaf(ga, w31, fmaf(gb, w32, bb3)));
            s3 += fmaxf(y3, 0.f);
            float z2 = fmaf(gz, u20, fmaf(g1, u21, cc2));
            t2 += fmaxf(z2, 0.f);
            float z3 = fmaf(gz, u30, fmaf(ga, u31, fmaf(gb, u32, cc3)));
            t3 += fmaxf(z3, 0.f);
        }
        am2[p] = s2 * 0.125f; am3[p] = s3 * 0.125f;
        av2[p] = t2 * 0.125f; av3[p] = t3 * 0.125f;
        if (r < 15) {
            mm_s[wid][r][k]      = am2[p];
            mm_s[wid][r][16 + k] = am3[p];
        }
    }
    __syncthreads();

    float xa = 0.f;
    #pragma unroll
    for (int half = 0; half < 2; ++half) {
        int r   = (lane >> 3) + half * 8;
        int doo = lane & 7;
        float s = 0.f;
        if (r < 15) {
            s = bzm_s[doo];
            #pragma unroll
            for (int c = 0; c < 32; ++c)
                s = fmaf(mm_s[wid][r][c], wmx_s[c][doo], s);
            s = fmaxf(s, 0.f);
        }
        xa += s;
    }
    xa += __shfl_xor(xa, 8);
    xa += __shfl_xor(xa, 16);
    xa += __shfl_xor(xa, 32);
    float xv = xa * (1.0f / 15.0f);
    if (lane < 8) xout[(long)pn * 8 + lane] = xv;

    float za = 0.f;
    #pragma unroll
    for (int r = 0; r < 15; ++r) {
        float s = bz3;
        const int p  = r >> 2;
        const int sb = (r & 3) * 16;
        #pragma unroll
        for (int c = 0; c < 16; ++c)
            s = fmaf(rl(av2[p], sb + c), wvx[c], s);
        #pragma unroll
        for (int c = 0; c < 16; ++c)
            s = fmaf(rl(av3[p], sb + c), wvx[16 + c], s);
        za += fmaxf(s, 0.f);
    }
    za *= (1.0f / 61440.0f);

    zpart[wid][lane] = za;
    __syncthreads();
    if (wid == 0) {
        float ssum = zpart[0][lane] + zpart[1][lane] + zpart[2][lane] + zpart[3][lane];
        atomicAdd(&zout[b * 64 + lane], ssum);
    }
}

// ---------- launcher ----------

extern "C" void kernel_launch(void* const* d_in, const int* in_sizes, int n_in,
                              void* d_out, int out_size, void* d_ws, size_t ws_size,
                              hipStream_t stream) {
    const float* x   = (const float*)d_in[0];
    const float* z   = (const float*)d_in[1];
    const float* Wm2 = (const float*)d_in[2];
    const float* bm2 = (const float*)d_in[3];
    const float* Wm3 = (const float*)d_in[4];
    const float* bm3 = (const float*)d_in[5];
    const float* Wv2 = (const float*)d_in[6];
    const float* bv2 = (const float*)d_in[7];
    const float* Wv3 = (const float*)d_in[8];
    const float* bv3 = (const float*)d_in[9];
    const float* Wmx = (const float*)d_in[10];
    const float* bmx = (const float*)d_in[11];
    const float* Wvx = (const float*)d_in[12];
    const float* bvx = (const float*)d_in[13];
    const float* Wmz = (const float*)d_in[14];
    const float* bmz = (const float*)d_in[15];
    const float* Wvz = (const float*)d_in[16];
    const float* bvz = (const float*)d_in[17];

    float* out  = (float*)d_out;
    int*   idxw = (int*)d_ws;                                   // 1 MB
    float* zzm  = (float*)((char*)d_ws + (size_t)BB * NPP * 16 * 4);
    float* zzv  = zzm + BB * 8;
    float* n2t  = zzv + BB * 64;                                // 64 KB
    float* xout = out;                 // B*NP*8 = 131072 floats
    float* zout = out + BB * NPP * 8;  // B*64 = 256 floats

    n2_kernel<<<dim3(BB * NPP / 256), dim3(256), 0, stream>>>(x, n2t, zout);
    zz_kernel<<<dim3(BB), dim3(64), 0, stream>>>(z, Wmz, bmz, Wvz, bvz, zzm, zzv);
    knn_kernel<<<dim3(BB * NPP / (4 * NQ)), dim3(256), 0, stream>>>(x, n2t, idxw);
    feat_kernel<<<dim3(4096), dim3(256), 0, stream>>>(
        x, idxw, Wm2, bm2, Wm3, bm3, Wv2, bv2, Wv3, bv3,
        Wmx, bmx, Wvx, bvx, zzm, zzv, xout, zout);
}